// Round 2
// baseline (446.678 us; speedup 1.0000x reference)
//
#include <hip/hip_runtime.h>

// Problem: B=1, S=I=H=4096. All tensors fp32 (inputs AND outputs).
// d_in: x(4096), hidden(4096), w_ih(12288*4096), w_hh(12288*4096),
//       b_ih(12288), b_hh(12288)
// d_out (fp32): outputs(4096*4096) ++ new_hidden(4096)
//
// Closed form of the reference scan:
//   g = [gi; gh] (24576 fp32) via GEMV
//   r = sig(gi_r+gh_r); z = sig(gi_z+gh_z); n = tanh(gi_n + r*gh_n)
//   a[s] = relu((1-z)*h + z*n)[s],  s in [0,4096)   (scalar per step s)
//   prefix[t] = inclusive_scan(a)[t]
//   outputs[t,j]  = prefix[t] + hidden[(j-t-1) & 4095]
//   new_hidden[j] = prefix[4095] + hidden[j]

#define H4 4096
#define R3 12288  // 3*H

// Native clang vector type: required by __builtin_nontemporal_store
// (HIP's float4 is a struct and is rejected).
typedef float floatx4 __attribute__((ext_vector_type(4)));

// ---------------- Kernel 1: GEMV (one wave per output row) ----------------
// rows 0..12287    : g[row] = dot(x,      w_ih[row])       + b_ih[row]
// rows 12288..24575: g[row] = dot(hidden, w_hh[row-12288]) + b_hh[row-12288]
//
// v2: (a) vector staged in LDS once per block (R3 % 4 == 0 so all 4 waves of
//     a block use the same vec) — removes 384 MiB of global v re-reads;
//     (b) 4 weight-quads in flight per chunk (VGPR budget raised from 16)
//     so each wave keeps ~6-8 b128 loads outstanding instead of 1.
__global__ __launch_bounds__(256, 6) void gemv_kernel(
    const float* __restrict__ x,
    const float* __restrict__ hidden,
    const float* __restrict__ w_ih,
    const float* __restrict__ w_hh,
    const float* __restrict__ b_ih,
    const float* __restrict__ b_hh,
    float* __restrict__ g) {
  __shared__ float4 vs[1024];  // 16 KiB: the block's input vector

  const int tid  = threadIdx.x;
  const int lane = tid & 63;
  const int widx = tid >> 6;
  const int wave = blockIdx.x * 4 + widx;  // 0..24575

  const float* vec;
  const float* wmat;
  const float* bias;
  int row;
  if (wave < R3) { vec = x;      wmat = w_ih; bias = b_ih; row = wave; }
  else           { vec = hidden; wmat = w_hh; bias = b_hh; row = wave - R3; }

  // Stage vec (16 KiB) into LDS, coalesced: 256 threads x 4 float4.
  const float4* vv = reinterpret_cast<const float4*>(vec);
#pragma unroll
  for (int k = 0; k < 4; ++k) vs[k * 256 + tid] = vv[k * 256 + tid];
  __syncthreads();

  const float4* wp =
      reinterpret_cast<const float4*>(wmat + (size_t)row * H4) + lane;

  float ax = 0.f, ay = 0.f, az = 0.f, aw = 0.f;
#pragma unroll
  for (int it = 0; it < 4; ++it) {
    // 4 independent 16B weight loads issued before any use -> MLP.
    float4 w0 = wp[0];
    float4 w1 = wp[64];
    float4 w2 = wp[128];
    float4 w3 = wp[192];
    wp += 256;
    float4 v0 = vs[it * 256 + lane];
    float4 v1 = vs[it * 256 + 64 + lane];
    float4 v2 = vs[it * 256 + 128 + lane];
    float4 v3 = vs[it * 256 + 192 + lane];
    ax = fmaf(w0.x, v0.x, ax); ay = fmaf(w0.y, v0.y, ay);
    az = fmaf(w0.z, v0.z, az); aw = fmaf(w0.w, v0.w, aw);
    ax = fmaf(w1.x, v1.x, ax); ay = fmaf(w1.y, v1.y, ay);
    az = fmaf(w1.z, v1.z, az); aw = fmaf(w1.w, v1.w, aw);
    ax = fmaf(w2.x, v2.x, ax); ay = fmaf(w2.y, v2.y, ay);
    az = fmaf(w2.z, v2.z, az); aw = fmaf(w2.w, v2.w, aw);
    ax = fmaf(w3.x, v3.x, ax); ay = fmaf(w3.y, v3.y, ay);
    az = fmaf(w3.z, v3.z, az); aw = fmaf(w3.w, v3.w, aw);
  }
  float acc = (ax + ay) + (az + aw);
#pragma unroll
  for (int s = 32; s > 0; s >>= 1) acc += __shfl_down(acc, s, 64);
  if (lane == 0) g[wave] = acc + bias[row];
}

// -------- Kernel 2: GRU combine + block-wide inclusive scan (1 block) -----
__global__ __launch_bounds__(1024) void combine_scan_kernel(
    const float* __restrict__ hidden,
    const float* __restrict__ g,
    float* __restrict__ prefix,
    float* __restrict__ out_newh) {
  const int tid = threadIdx.x;
  const int s0 = tid * 4;

  float a[4];
#pragma unroll
  for (int k = 0; k < 4; ++k) {
    const int s = s0 + k;
    const float r = 1.f / (1.f + __expf(-(g[s] + g[R3 + s])));
    const float z = 1.f / (1.f + __expf(-(g[H4 + s] + g[R3 + H4 + s])));
    const float n = tanhf(g[2 * H4 + s] + r * g[R3 + 2 * H4 + s]);
    const float h = hidden[s];
    const float b = (1.f - z) * h + z * n;
    a[k] = fmaxf(b, 0.f);
  }
  const float c0 = a[0], c1 = c0 + a[1], c2 = c1 + a[2], c3 = c2 + a[3];
  const float tsum = c3;

  const int lane = tid & 63, wid = tid >> 6;
  float v = tsum;
#pragma unroll
  for (int d = 1; d < 64; d <<= 1) {
    float o = __shfl_up(v, d, 64);
    if (lane >= d) v += o;
  }
  __shared__ float wsum[16];
  if (lane == 63) wsum[wid] = v;
  __syncthreads();
  if (tid < 16) {
    float w = wsum[tid];
#pragma unroll
    for (int d = 1; d < 16; d <<= 1) {
      float o = __shfl_up(w, d, 64);
      if (tid >= d) w += o;
    }
    wsum[tid] = w;
  }
  __syncthreads();

  const float excl = (wid ? wsum[wid - 1] : 0.f) + (v - tsum);
  prefix[s0 + 0] = excl + c0;
  prefix[s0 + 1] = excl + c1;
  prefix[s0 + 2] = excl + c2;
  prefix[s0 + 3] = excl + c3;

  const float total = wsum[15];
#pragma unroll
  for (int k = 0; k < 4; ++k) {
    const int s = s0 + k;
    out_newh[s] = total + hidden[s];
  }
}

// ------- Kernel 3: outputs[t,j] = prefix[t] + hidden[(j-t-1)&4095] --------
// One block covers half a row (2048 floats); each thread writes 8 floats
// (two float4 stores, 32 B). Non-temporal stores: the 64 MiB output has no
// reuse — keep it from evicting the weight working set out of L3.
__global__ __launch_bounds__(256) void outputs_kernel(
    const float* __restrict__ prefix,
    const float* __restrict__ hidden,
    float* __restrict__ out) {
  const int b = blockIdx.x;
  const int t = b >> 1;
  const int j0 = (b & 1) * 2048 + threadIdx.x * 8;
  const float p = prefix[t];
  const int base = (j0 - t - 1) & 4095;

  floatx4 o0, o1;
  o0.x = p + hidden[base];
  o0.y = p + hidden[(base + 1) & 4095];
  o0.z = p + hidden[(base + 2) & 4095];
  o0.w = p + hidden[(base + 3) & 4095];
  o1.x = p + hidden[(base + 4) & 4095];
  o1.y = p + hidden[(base + 5) & 4095];
  o1.z = p + hidden[(base + 6) & 4095];
  o1.w = p + hidden[(base + 7) & 4095];

  float* dst = out + (size_t)t * H4 + j0;
  __builtin_nontemporal_store(o0, reinterpret_cast<floatx4*>(dst));
  __builtin_nontemporal_store(o1, reinterpret_cast<floatx4*>(dst + 4));
}

extern "C" void kernel_launch(void* const* d_in, const int* in_sizes, int n_in,
                              void* d_out, int out_size, void* d_ws, size_t ws_size,
                              hipStream_t stream) {
  const float* x      = (const float*)d_in[0];
  const float* hidden = (const float*)d_in[1];
  const float* w_ih   = (const float*)d_in[2];
  const float* w_hh   = (const float*)d_in[3];
  const float* b_ih   = (const float*)d_in[4];
  const float* b_hh   = (const float*)d_in[5];
  float* out = (float*)d_out;

  float* ws     = (float*)d_ws;
  float* g      = ws;          // 24576 fp32
  float* prefix = ws + 24576;  // 4096 fp32

  // 24576 rows, 4 waves/block -> 6144 blocks
  gemv_kernel<<<6144, 256, 0, stream>>>(x, hidden, w_ih, w_hh, b_ih, b_hh, g);
  combine_scan_kernel<<<1, 1024, 0, stream>>>(hidden, g, prefix,
                                              out + (size_t)H4 * H4);
  outputs_kernel<<<8192, 256, 0, stream>>>(prefix, hidden, out);
}

// Round 3
// 419.847 us; speedup vs baseline: 1.0639x; 1.0639x over previous
//
#include <hip/hip_runtime.h>

// Problem: B=1, S=I=H=4096. All tensors fp32 (inputs AND outputs).
// d_in: x(4096), hidden(4096), w_ih(12288*4096), w_hh(12288*4096),
//       b_ih(12288), b_hh(12288)
// d_out (fp32): outputs(4096*4096) ++ new_hidden(4096)
//
// Closed form of the reference scan:
//   g = [gi; gh] (24576 fp32) via GEMV
//   r = sig(gi_r+gh_r); z = sig(gi_z+gh_z); n = tanh(gi_n + r*gh_n)
//   a[s] = relu((1-z)*h + z*n)[s],  s in [0,4096)   (scalar per step s)
//   prefix[t] = inclusive_scan(a)[t]
//   outputs[t,j]  = prefix[t] + hidden[(j-t-1) & 4095]
//   new_hidden[j] = prefix[4095] + hidden[j]

#define H4 4096
#define R3 12288  // 3*H

// Native clang vector type: required by __builtin_nontemporal_{load,store}
// (HIP's float4 is a struct and is rejected).
typedef float floatx4 __attribute__((ext_vector_type(4)));

// ---------------- Kernel 1: GEMV (one wave per output row) ----------------
// rows 0..12287    : g[row] = dot(x,      w_ih[row])       + b_ih[row]
// rows 12288..24575: g[row] = dot(hidden, w_hh[row-12288]) + b_hh[row-12288]
//
// v3 theory: the 384 MiB weight stream thrashes the 256 MiB L3 every
// iteration; the mixed L3-hit/HBM-miss read path plateaus at ~3.2 TB/s
// (v2 measured: 197 MB FETCH + ~205 MB L3-served in 124 us, VALUBusy 4%,
// zero bank conflicts — a bandwidth wall, not latency/MLP).
// Fix: (a) NON-TEMPORAL weight loads — stream from HBM, don't allocate in
// L3; (b) all 16 row-quads issued up-front (256 KiB outstanding/CU at 16
// waves/CU) so we stay BW-bound even under latency inflation.
__global__ __launch_bounds__(256, 4) void gemv_kernel(
    const float* __restrict__ x,
    const float* __restrict__ hidden,
    const float* __restrict__ w_ih,
    const float* __restrict__ w_hh,
    const float* __restrict__ b_ih,
    const float* __restrict__ b_hh,
    float* __restrict__ g) {
  __shared__ floatx4 vs[1024];  // 16 KiB: the block's input vector

  const int tid  = threadIdx.x;
  const int lane = tid & 63;
  const int widx = tid >> 6;
  const int wave = blockIdx.x * 4 + widx;  // 0..24575

  const float* vec;
  const float* wmat;
  const float* bias;
  int row;
  if (wave < R3) { vec = x;      wmat = w_ih; bias = b_ih; row = wave; }
  else           { vec = hidden; wmat = w_hh; bias = b_hh; row = wave - R3; }

  // Stage vec (16 KiB) into LDS, coalesced: 256 threads x 4 float4.
  const floatx4* vv = reinterpret_cast<const floatx4*>(vec);
#pragma unroll
  for (int k = 0; k < 4; ++k) vs[k * 256 + tid] = vv[k * 256 + tid];
  __syncthreads();  // drains only the 4 staging stores (weights not issued yet)

  const floatx4* wp =
      reinterpret_cast<const floatx4*>(wmat + (size_t)row * H4) + lane;

  // Issue ALL 16 weight quads (256 B/lane, 16 KiB/wave) before any use.
  // Fully unrolled -> static indices -> registers (64 VGPRs).
  floatx4 w[16];
#pragma unroll
  for (int it = 0; it < 16; ++it)
    w[it] = __builtin_nontemporal_load(wp + it * 64);

  float ax = 0.f, ay = 0.f, az = 0.f, aw = 0.f;
#pragma unroll
  for (int it = 0; it < 16; ++it) {
    floatx4 v = vs[it * 64 + lane];
    ax = fmaf(w[it].x, v.x, ax);
    ay = fmaf(w[it].y, v.y, ay);
    az = fmaf(w[it].z, v.z, az);
    aw = fmaf(w[it].w, v.w, aw);
  }
  float acc = (ax + ay) + (az + aw);
#pragma unroll
  for (int s = 32; s > 0; s >>= 1) acc += __shfl_down(acc, s, 64);
  if (lane == 0) g[wave] = acc + bias[row];
}

// -------- Kernel 2: GRU combine + block-wide inclusive scan (1 block) -----
__global__ __launch_bounds__(1024) void combine_scan_kernel(
    const float* __restrict__ hidden,
    const float* __restrict__ g,
    float* __restrict__ prefix,
    float* __restrict__ out_newh) {
  const int tid = threadIdx.x;
  const int s0 = tid * 4;

  float a[4];
#pragma unroll
  for (int k = 0; k < 4; ++k) {
    const int s = s0 + k;
    const float r = 1.f / (1.f + __expf(-(g[s] + g[R3 + s])));
    const float z = 1.f / (1.f + __expf(-(g[H4 + s] + g[R3 + H4 + s])));
    const float n = tanhf(g[2 * H4 + s] + r * g[R3 + 2 * H4 + s]);
    const float h = hidden[s];
    const float b = (1.f - z) * h + z * n;
    a[k] = fmaxf(b, 0.f);
  }
  const float c0 = a[0], c1 = c0 + a[1], c2 = c1 + a[2], c3 = c2 + a[3];
  const float tsum = c3;

  const int lane = tid & 63, wid = tid >> 6;
  float v = tsum;
#pragma unroll
  for (int d = 1; d < 64; d <<= 1) {
    float o = __shfl_up(v, d, 64);
    if (lane >= d) v += o;
  }
  __shared__ float wsum[16];
  if (lane == 63) wsum[wid] = v;
  __syncthreads();
  if (tid < 16) {
    float w = wsum[tid];
#pragma unroll
    for (int d = 1; d < 16; d <<= 1) {
      float o = __shfl_up(w, d, 64);
      if (tid >= d) w += o;
    }
    wsum[tid] = w;
  }
  __syncthreads();

  const float excl = (wid ? wsum[wid - 1] : 0.f) + (v - tsum);
  prefix[s0 + 0] = excl + c0;
  prefix[s0 + 1] = excl + c1;
  prefix[s0 + 2] = excl + c2;
  prefix[s0 + 3] = excl + c3;

  const float total = wsum[15];
#pragma unroll
  for (int k = 0; k < 4; ++k) {
    const int s = s0 + k;
    out_newh[s] = total + hidden[s];
  }
}

// ------- Kernel 3: outputs[t,j] = prefix[t] + hidden[(j-t-1)&4095] --------
// One block covers half a row (2048 floats); each thread writes 8 floats
// (two float4 stores, 32 B). Non-temporal stores: the 64 MiB output has no
// reuse — keep it from evicting anything useful out of L3.
__global__ __launch_bounds__(256) void outputs_kernel(
    const float* __restrict__ prefix,
    const float* __restrict__ hidden,
    float* __restrict__ out) {
  const int b = blockIdx.x;
  const int t = b >> 1;
  const int j0 = (b & 1) * 2048 + threadIdx.x * 8;
  const float p = prefix[t];
  const int base = (j0 - t - 1) & 4095;

  floatx4 o0, o1;
  o0.x = p + hidden[base];
  o0.y = p + hidden[(base + 1) & 4095];
  o0.z = p + hidden[(base + 2) & 4095];
  o0.w = p + hidden[(base + 3) & 4095];
  o1.x = p + hidden[(base + 4) & 4095];
  o1.y = p + hidden[(base + 5) & 4095];
  o1.z = p + hidden[(base + 6) & 4095];
  o1.w = p + hidden[(base + 7) & 4095];

  float* dst = out + (size_t)t * H4 + j0;
  __builtin_nontemporal_store(o0, reinterpret_cast<floatx4*>(dst));
  __builtin_nontemporal_store(o1, reinterpret_cast<floatx4*>(dst + 4));
}

extern "C" void kernel_launch(void* const* d_in, const int* in_sizes, int n_in,
                              void* d_out, int out_size, void* d_ws, size_t ws_size,
                              hipStream_t stream) {
  const float* x      = (const float*)d_in[0];
  const float* hidden = (const float*)d_in[1];
  const float* w_ih   = (const float*)d_in[2];
  const float* w_hh   = (const float*)d_in[3];
  const float* b_ih   = (const float*)d_in[4];
  const float* b_hh   = (const float*)d_in[5];
  float* out = (float*)d_out;

  float* ws     = (float*)d_ws;
  float* g      = ws;          // 24576 fp32
  float* prefix = ws + 24576;  // 4096 fp32

  // 24576 rows, 4 waves/block -> 6144 blocks
  gemv_kernel<<<6144, 256, 0, stream>>>(x, hidden, w_ih, w_hh, b_ih, b_hh, g);
  combine_scan_kernel<<<1, 1024, 0, stream>>>(hidden, g, prefix,
                                              out + (size_t)H4 * H4);
  outputs_kernel<<<8192, 256, 0, stream>>>(prefix, hidden, out);
}

// Round 4
// 417.020 us; speedup vs baseline: 1.0711x; 1.0068x over previous
//
#include <hip/hip_runtime.h>

// Problem: B=1, S=I=H=4096. All tensors fp32 (inputs AND outputs).
// d_in: x(4096), hidden(4096), w_ih(12288*4096), w_hh(12288*4096),
//       b_ih(12288), b_hh(12288)
// d_out (fp32): outputs(4096*4096) ++ new_hidden(4096)
//
// Closed form of the reference scan:
//   g = [gi; gh] (24576 fp32) via GEMV
//   r = sig(gi_r+gh_r); z = sig(gi_z+gh_z); n = tanh(gi_n + r*gh_n)
//   a[s] = relu((1-z)*h + z*n)[s],  s in [0,4096)   (scalar per step s)
//   prefix[t] = inclusive_scan(a)[t]
//   outputs[t,j]  = prefix[t] + hidden[(j-t-1) & 4095]
//   new_hidden[j] = prefix[4095] + hidden[j]

#define H4 4096
#define R3 12288  // 3*H

// Native clang vector type: required by __builtin_nontemporal_{load,store}
// (HIP's float4 is a struct and is rejected).
typedef float floatx4 __attribute__((ext_vector_type(4)));

// ---------------- Kernel 1: GEMV (one wave per output row) ----------------
// rows 0..12287    : g[row] = dot(x,      w_ih[row])       + b_ih[row]
// rows 12288..24575: g[row] = dot(hidden, w_hh[row-12288]) + b_hh[row-12288]
//
// v4: NT weight loads proved out (v3: 3.2 -> 4.1 TB/s effective read).
// Remaining gap to ~6.6 TB/s blamed on the per-block LDS stage + barrier:
// it delays first weight-load issue at every block churn (24 per CU) and
// the vec path was proven irrelevant in v2 (L2-hot, FETCH unchanged).
// So: NO LDS, NO barrier — each wave's first instructions are its 16 NT
// weight loads; vec comes from L1/L2, scheduled behind them.
__global__ __launch_bounds__(256, 4) void gemv_kernel(
    const float* __restrict__ x,
    const float* __restrict__ hidden,
    const float* __restrict__ w_ih,
    const float* __restrict__ w_hh,
    const float* __restrict__ b_ih,
    const float* __restrict__ b_hh,
    float* __restrict__ g) {
  const int tid  = threadIdx.x;
  const int lane = tid & 63;
  const int widx = tid >> 6;
  const int wave = blockIdx.x * 4 + widx;  // 0..24575

  const float* vec;
  const float* wmat;
  const float* bias;
  int row;
  if (wave < R3) { vec = x;      wmat = w_ih; bias = b_ih; row = wave; }
  else           { vec = hidden; wmat = w_hh; bias = b_hh; row = wave - R3; }

  const floatx4* wp =
      reinterpret_cast<const floatx4*>(wmat + (size_t)row * H4) + lane;
  const floatx4* vv = reinterpret_cast<const floatx4*>(vec) + lane;

  // Issue ALL 16 weight quads (256 B/lane, 16 KiB/wave) before anything
  // else. Fully unrolled -> static indices -> registers (64 VGPRs).
  floatx4 w[16];
#pragma unroll
  for (int it = 0; it < 16; ++it)
    w[it] = __builtin_nontemporal_load(wp + it * 64);

  float ax = 0.f, ay = 0.f, az = 0.f, aw = 0.f;
#pragma unroll
  for (int it = 0; it < 16; ++it) {
    floatx4 v = vv[it * 64];  // L1/L2-hot (vec is 16 KiB, read by all waves)
    ax = fmaf(w[it].x, v.x, ax);
    ay = fmaf(w[it].y, v.y, ay);
    az = fmaf(w[it].z, v.z, az);
    aw = fmaf(w[it].w, v.w, aw);
  }
  float acc = (ax + ay) + (az + aw);
#pragma unroll
  for (int s = 32; s > 0; s >>= 1) acc += __shfl_down(acc, s, 64);
  if (lane == 0) g[wave] = acc + bias[row];
}

// -------- Kernel 2: GRU combine + block-wide inclusive scan (1 block) -----
__global__ __launch_bounds__(1024) void combine_scan_kernel(
    const float* __restrict__ hidden,
    const float* __restrict__ g,
    float* __restrict__ prefix,
    float* __restrict__ out_newh) {
  const int tid = threadIdx.x;
  const int s0 = tid * 4;

  float a[4];
#pragma unroll
  for (int k = 0; k < 4; ++k) {
    const int s = s0 + k;
    const float r = 1.f / (1.f + __expf(-(g[s] + g[R3 + s])));
    const float z = 1.f / (1.f + __expf(-(g[H4 + s] + g[R3 + H4 + s])));
    const float n = tanhf(g[2 * H4 + s] + r * g[R3 + 2 * H4 + s]);
    const float h = hidden[s];
    const float b = (1.f - z) * h + z * n;
    a[k] = fmaxf(b, 0.f);
  }
  const float c0 = a[0], c1 = c0 + a[1], c2 = c1 + a[2], c3 = c2 + a[3];
  const float tsum = c3;

  const int lane = tid & 63, wid = tid >> 6;
  float v = tsum;
#pragma unroll
  for (int d = 1; d < 64; d <<= 1) {
    float o = __shfl_up(v, d, 64);
    if (lane >= d) v += o;
  }
  __shared__ float wsum[16];
  if (lane == 63) wsum[wid] = v;
  __syncthreads();
  if (tid < 16) {
    float w = wsum[tid];
#pragma unroll
    for (int d = 1; d < 16; d <<= 1) {
      float o = __shfl_up(w, d, 64);
      if (tid >= d) w += o;
    }
    wsum[tid] = w;
  }
  __syncthreads();

  const float excl = (wid ? wsum[wid - 1] : 0.f) + (v - tsum);
  prefix[s0 + 0] = excl + c0;
  prefix[s0 + 1] = excl + c1;
  prefix[s0 + 2] = excl + c2;
  prefix[s0 + 3] = excl + c3;

  const float total = wsum[15];
#pragma unroll
  for (int k = 0; k < 4; ++k) {
    const int s = s0 + k;
    out_newh[s] = total + hidden[s];
  }
}

// ------- Kernel 3: outputs[t,j] = prefix[t] + hidden[(j-t-1)&4095] --------
// One block covers half a row (2048 floats); each thread writes 8 floats
// (two float4 stores, 32 B). Non-temporal stores: the 64 MiB output has no
// reuse — keep it from evicting anything useful out of L3.
__global__ __launch_bounds__(256) void outputs_kernel(
    const float* __restrict__ prefix,
    const float* __restrict__ hidden,
    float* __restrict__ out) {
  const int b = blockIdx.x;
  const int t = b >> 1;
  const int j0 = (b & 1) * 2048 + threadIdx.x * 8;
  const float p = prefix[t];
  const int base = (j0 - t - 1) & 4095;

  floatx4 o0, o1;
  o0.x = p + hidden[base];
  o0.y = p + hidden[(base + 1) & 4095];
  o0.z = p + hidden[(base + 2) & 4095];
  o0.w = p + hidden[(base + 3) & 4095];
  o1.x = p + hidden[(base + 4) & 4095];
  o1.y = p + hidden[(base + 5) & 4095];
  o1.z = p + hidden[(base + 6) & 4095];
  o1.w = p + hidden[(base + 7) & 4095];

  float* dst = out + (size_t)t * H4 + j0;
  __builtin_nontemporal_store(o0, reinterpret_cast<floatx4*>(dst));
  __builtin_nontemporal_store(o1, reinterpret_cast<floatx4*>(dst + 4));
}

extern "C" void kernel_launch(void* const* d_in, const int* in_sizes, int n_in,
                              void* d_out, int out_size, void* d_ws, size_t ws_size,
                              hipStream_t stream) {
  const float* x      = (const float*)d_in[0];
  const float* hidden = (const float*)d_in[1];
  const float* w_ih   = (const float*)d_in[2];
  const float* w_hh   = (const float*)d_in[3];
  const float* b_ih   = (const float*)d_in[4];
  const float* b_hh   = (const float*)d_in[5];
  float* out = (float*)d_out;

  float* ws     = (float*)d_ws;
  float* g      = ws;          // 24576 fp32
  float* prefix = ws + 24576;  // 4096 fp32

  // 24576 rows, 4 waves/block -> 6144 blocks
  gemv_kernel<<<6144, 256, 0, stream>>>(x, hidden, w_ih, w_hh, b_ih, b_hh, g);
  combine_scan_kernel<<<1, 1024, 0, stream>>>(hidden, g, prefix,
                                              out + (size_t)H4 * H4);
  outputs_kernel<<<8192, 256, 0, stream>>>(prefix, hidden, out);
}